// Round 17
// baseline (136.516 us; speedup 1.0000x reference)
//
#include <hip/hip_runtime.h>
#include <hip/hip_fp16.h>
#include <math.h>

#define EPS 1e-16f
#define LOG2E 1.44269504088896340736f

typedef _Float16 half8 __attribute__((ext_vector_type(8)));
typedef float floatx4 __attribute__((ext_vector_type(4)));

// CSR-build geometry: 4 dst-ranges x 16384 nodes (64KB LDS histogram),
// 64 edge-chunk blocks per range -> 256 blocks (all CUs).
#define RNG 4
#define NRR 16384
#define RB  64

// ---------------- fused: hist (blocks < 256) + misc x->fp16 / W1 pack / wed (rest) ------

__global__ __launch_bounds__(256) void k_prephist(
    int E, int CH, const int* __restrict__ ei,
    unsigned short* __restrict__ H, unsigned short* __restrict__ rank,
    int N, int nbX, const float* __restrict__ x, _Float16* __restrict__ xh,
    const float* __restrict__ W1, _Float16* __restrict__ Wpk,
    const float* __restrict__ We1, const float* __restrict__ ae1,
    const float* __restrict__ We2, const float* __restrict__ ae2,
    float* __restrict__ wed, int* __restrict__ done) {
    __shared__ int hist[NRR];
    int bid = blockIdx.x;
    if (bid < RNG * RB) {
        // ---- histogram ----
        int r = bid / RB, b = bid % RB;
        for (int i = threadIdx.x; i < NRR; i += 256) hist[i] = 0;
        __syncthreads();
        int lo = b * CH, hi = min(E, (b + 1) * CH);
        int rlo = r << 14;
#pragma unroll 4
        for (int e = lo + threadIdx.x; e < hi; e += 256) {
            int d = ei[E + e];
            int dr = d - rlo;
            if ((unsigned)dr < NRR) rank[e] = (unsigned short)atomicAdd(&hist[dr], 1);
        }
        __syncthreads();
        unsigned short* Hb = H + (size_t)bid * NRR;
        for (int i = threadIdx.x; i < NRR; i += 256) Hb[i] = (unsigned short)hist[i];
        return;
    }
    int mb = bid - RNG * RB;
    if (mb < nbX) {
        // ---- x -> fp16, zero-padded ----
        int t = mb * 256 + threadIdx.x;
        int row = t >> 3;
        half8 h;
        if (row < N) {
            const float4* pp = (const float4*)(x + (size_t)t * 8);
            float4 f0 = pp[0], f1 = pp[1];
            h[0] = (_Float16)f0.x; h[1] = (_Float16)f0.y; h[2] = (_Float16)f0.z; h[3] = (_Float16)f0.w;
            h[4] = (_Float16)f1.x; h[5] = (_Float16)f1.y; h[6] = (_Float16)f1.z; h[7] = (_Float16)f1.w;
        } else {
#pragma unroll
            for (int i = 0; i < 8; ++i) h[i] = (_Float16)0.0f;
        }
        *(half8*)(xh + (size_t)t * 8) = h;
    } else {
        // ---- W1 -> MFMA B-fragment order + wed dots (pre-scaled by log2e) ----
        int t = threadIdx.x;
        for (int i = 0; i < 32; ++i) {
            int idx = i * 256 + t;           // 8192 total
            int j  = idx & 7;
            int lq = (idx >> 3) & 63;
            int ks = (idx >> 9) & 1;
            int ct = idx >> 10;
            int k   = ks * 32 + (lq >> 4) * 8 + j;
            int col = ct * 16 + (lq & 15);
            Wpk[idx] = (_Float16)W1[k * 128 + col];
        }
        if (t < 8) {
            float ssum = 0.0f;
            for (int cc = 0; cc < 16; ++cc) ssum += We1[t * 16 + cc] * ae1[t * 16 + cc];
            wed[t] = ssum * LOG2E;
        }
        if (t == 8) {
            float ssum = 0.0f;
            for (int cc = 0; cc < 8; ++cc) ssum += We2[cc] * ae2[cc];
            wed[8] = ssum * LOG2E;
        }
        if (t == 9) *done = 0;   // reset last-block counter every launch (graph replay safe)
    }
}

// fused: per-node scan of the RB block-histograms (in place, u16) + block-LOCAL
// exclusive scan of cnt into rowptr + bsums; the LAST block to finish computes the
// 196-entry block prefix bpref in-kernel (threadfence + atomic pattern, G12/G16).
__global__ __launch_bounds__(256) void k_cntscan(
    int N, int nbN, unsigned short* __restrict__ H,
    int* __restrict__ rowptr, int* __restrict__ bsums,
    int* __restrict__ bpref, int* __restrict__ done) {
    __shared__ int sm[256];
    __shared__ int isLast;
    int t = threadIdx.x;
    int n = blockIdx.x * 256 + t;
    int sum = 0;
    if (n < N) {
        int r = n >> 14, dr = n & (NRR - 1);
        size_t base = ((size_t)(r * RB)) * NRR + dr;
#pragma unroll 8
        for (int b = 0; b < RB; ++b) {
            size_t idx = base + (size_t)b * NRR;
            int v = H[idx];
            H[idx] = (unsigned short)sum;
            sum += v;
        }
    }
    int val = (n < N) ? sum : 0;
    sm[t] = val; __syncthreads();
    for (int ofs = 1; ofs < 256; ofs <<= 1) {
        int v = (t >= ofs) ? sm[t - ofs] : 0;
        __syncthreads();
        sm[t] += v;
        __syncthreads();
    }
    if (n < N) rowptr[n] = sm[t] - val;     // block-local exclusive
    if (n == N - 1) rowptr[N] = sm[t];      // local inclusive tail
    if (t == 255) bsums[blockIdx.x] = sm[255];
    __threadfence();                        // release this block's writes device-wide
    __syncthreads();
    if (t == 0) isLast = (atomicAdd(done, 1) == nbN - 1);
    __syncthreads();
    if (!isLast) return;
    __threadfence();                        // acquire: invalidate stale lines
    int v2 = (t < nbN) ? bsums[t] : 0;
    __syncthreads();                        // sm reuse guard
    sm[t] = v2; __syncthreads();
    for (int ofs = 1; ofs < 256; ofs <<= 1) {
        int u = (t >= ofs) ? sm[t - ofs] : 0;
        __syncthreads();
        sm[t] += u;
        __syncthreads();
    }
    if (t < nbN) bpref[t] = sm[t] - v2;     // exclusive block prefix
    if (t == nbN - 1) bpref[nbN] = sm[t];   // total
}

// ---------------- fused: scatter (blocks < SB) + layer-1 MFMA gemm (rest) ----------------
// 128-thread blocks; scatter handles 2 edges/thread (2x outstanding stores);
// gemm uses a 2-wave 16.9KB LDS slab so scatter occupancy stays high.

#define LDSP 132

__global__ __launch_bounds__(128) void k_scatgemm(
    int E, int CH, int SB, const int* __restrict__ ei, const float* __restrict__ ea,
    const int* __restrict__ rowptr, const int* __restrict__ bpref,
    const unsigned short* __restrict__ H,
    const unsigned short* __restrict__ rank, int2* __restrict__ rec,
    int N, const _Float16* __restrict__ xh, const _Float16* __restrict__ Wpk,
    const float* __restrict__ att_s, const float* __restrict__ att_d,
    __half* __restrict__ h1, float* __restrict__ asrc, float* __restrict__ adst) {
    __shared__ float hs[2 * 16 * LDSP];
    if ((int)blockIdx.x < SB) {
        // ---- scatter: 2 packed 8B stores per thread + sentinel pads ----
        int base = blockIdx.x * 256 + threadIdx.x;
#pragma unroll
        for (int q = 0; q < 2; ++q) {
            int e = base + q * 128;
            if (e < E) {
                int s = ei[e], d = ei[E + e];
                int r = d >> 14, dr = d & (NRR - 1);
                int b = e / CH;
                int pos = rowptr[d] + bpref[d >> 8]
                        + (int)H[((size_t)(r * RB + b)) * NRR + dr] + (int)rank[e];
                rec[pos] = make_int2(s, __float_as_int(ea[e]));
            } else if (e < E + 32) {
                rec[e] = make_int2(0, 0);    // sentinel pad: valid node id, attr 0
            }
        }
        return;
    }
    // ---- gemm: 32-row tile; wave w computes rows [blk*32+w*16,+16) x 128 ----
    int blk = blockIdx.x - SB;
    int tid = threadIdx.x;
    int w = tid >> 6, l = tid & 63;
    int row0 = blk * 32 + w * 16;
    int arow = row0 + (l & 15);
    half8 a0 = *(const half8*)(xh + (size_t)arow * 64 + (l >> 4) * 8);
    half8 a1 = *(const half8*)(xh + (size_t)arow * 64 + 32 + (l >> 4) * 8);
    float* base = &hs[w * 16 * LDSP];
    int r0 = (l >> 4) * 4;
#pragma unroll
    for (int ct = 0; ct < 8; ++ct) {
        half8 b0 = *(const half8*)(Wpk + ((ct * 2 + 0) * 64 + l) * 8);
        half8 b1 = *(const half8*)(Wpk + ((ct * 2 + 1) * 64 + l) * 8);
        floatx4 acc = {0.f, 0.f, 0.f, 0.f};
        acc = __builtin_amdgcn_mfma_f32_16x16x32_f16(a0, b0, acc, 0, 0, 0);
        acc = __builtin_amdgcn_mfma_f32_16x16x32_f16(a1, b1, acc, 0, 0, 0);
        int col = ct * 16 + (l & 15);
#pragma unroll
        for (int i = 0; i < 4; ++i)
            base[(r0 + i) * LDSP + col] = acc[i];
    }
    __syncthreads();
    int r = tid >> 2, g = tid & 3;      // r in 0..31
    int rg = blk * 32 + r;
    if (rg >= N) return;
    float v[32];
    const float* rp = &hs[r * LDSP + g * 32];
#pragma unroll
    for (int j = 0; j < 8; ++j) {
        floatx4 t4 = *(const floatx4*)(rp + j * 4);
        v[j * 4 + 0] = t4[0]; v[j * 4 + 1] = t4[1];
        v[j * 4 + 2] = t4[2]; v[j * 4 + 3] = t4[3];
    }
    float vs0 = 0.f, vs1 = 0.f, vd0 = 0.f, vd1 = 0.f;
    const float4* as4 = (const float4*)(att_s + g * 32);
    const float4* ad4 = (const float4*)(att_d + g * 32);
#pragma unroll
    for (int j = 0; j < 4; ++j) {
        float4 a4 = as4[j], d4 = ad4[j];
        vs0 += v[j*4+0]*a4.x + v[j*4+1]*a4.y + v[j*4+2]*a4.z + v[j*4+3]*a4.w;
        vd0 += v[j*4+0]*d4.x + v[j*4+1]*d4.y + v[j*4+2]*d4.z + v[j*4+3]*d4.w;
    }
#pragma unroll
    for (int j = 4; j < 8; ++j) {
        float4 a4 = as4[j], d4 = ad4[j];
        vs1 += v[j*4+0]*a4.x + v[j*4+1]*a4.y + v[j*4+2]*a4.z + v[j*4+3]*a4.w;
        vd1 += v[j*4+0]*d4.x + v[j*4+1]*d4.y + v[j*4+2]*d4.z + v[j*4+3]*d4.w;
    }
    union { __half h[32]; float4 f4[4]; } u;
#pragma unroll
    for (int i = 0; i < 32; ++i) u.h[i] = __float2half(v[i]);
    float4* hp = (float4*)(h1 + (size_t)rg * 128 + g * 32);
#pragma unroll
    for (int j = 0; j < 4; ++j) hp[j] = u.f4[j];
    asrc[rg * 8 + g * 2]     = vs0 * LOG2E;
    asrc[rg * 8 + g * 2 + 1] = vs1 * LOG2E;
    adst[rg * 8 + g * 2]     = vd0 * LOG2E;
    adst[rg * 8 + g * 2 + 1] = vd1 * LOG2E;
}

// ---------------- layer 1 aggregation (virtual self-loop, clamp-free) + fused L2 dense --
// one wave per node; lane l = (eo = l>>3 edge slot, hd = l&7 head). rec is padded with
// 32 sentinels -> no min/has clamps; invalid lanes masked by e<end only.
// rowptr is block-local; segment bounds add bpref (L2-hot).

__global__ __launch_bounds__(256) void k_agg1(
    int N, const int* __restrict__ rowptr, const int* __restrict__ bpref,
    const int2* __restrict__ rec,
    const float* __restrict__ asrc1, const float* __restrict__ adst1,
    const float* __restrict__ wed,
    const __half* __restrict__ h1v, const float* __restrict__ b1,
    const float* __restrict__ W2, const float* __restrict__ as2w, const float* __restrict__ ad2w,
    float* __restrict__ hh2, float* __restrict__ asrc2, float* __restrict__ adst2) {
    __shared__ float hs[4 * 1040];   // 4 waves x 16 rows x 65 floats (stride 65: conflict-free)
    int tid = threadIdx.x;
    int wid = (blockIdx.x * blockDim.x + tid) >> 6;
    if (wid >= N) return;
    int l = tid & 63, w = tid >> 6;
    int eo = l >> 3, hd = l & 7;
    int start = rowptr[wid] + bpref[wid >> 8];
    int end   = rowptr[wid + 1] + bpref[(wid + 1) >> 8];
    int len = end - start;               // real edges
    float adn = adst1[wid * 8 + hd];     // pre-scaled by log2e
    float wdh = wed[hd];                 // pre-scaled by log2e
    const _Float16* h1p = (const _Float16*)h1v;

    // self-loop row: issue early, consume in epilogue
    const _Float16* hrs = h1p + (((size_t)wid) << 7) + hd * 16;
    float4 sv0 = *(const float4*)hrs;
    float4 sv1 = *(const float4*)(hrs + 8);
    float aslf = asrc1[wid * 8 + hd];

    float acc[16];
#pragma unroll
    for (int k = 0; k < 16; ++k) acc[k] = 0.f;
    float denom = 0.f, esum = 0.f;
    int e = start + eo;
    int2 rv  = rec[e];
    int2 rn1 = rec[e + 8];
    float av = asrc1[rv.x * 8 + hd];
    int nIt = (len + 7) >> 3;
    for (int it = 0; it < nIt; ++it) {
        const _Float16* hr = h1p + (((size_t)rv.x) << 7) + hd * 16;
        float4 hv0 = *(const float4*)hr;          // addr register-ready (rv 2 iters old)
        float4 hv1 = *(const float4*)(hr + 8);
        int2 rn2 = rec[e + 16];                   // 2-ahead rec (pad-safe)
        float an = asrc1[rn1.x * 8 + hd];         // 1-ahead asrc
        float wgt = __int_as_float(rv.y);
        __builtin_amdgcn_s_setprio(1);
        float a = av + adn + wgt * wdh;
        a = fmaxf(a, 0.2f * a);                   // leaky-relu (scale-commutes)
        bool valid = (e < end);
        float p = valid ? exp2f(a) : 0.f;
        esum += valid ? wgt : 0.f;
        denom += p;
        const _Float16* x0 = (const _Float16*)&hv0;
        const _Float16* x1 = (const _Float16*)&hv1;
#pragma unroll
        for (int k = 0; k < 8; ++k) acc[k]     = fmaf(p, (float)x0[k], acc[k]);
#pragma unroll
        for (int k = 0; k < 8; ++k) acc[8 + k] = fmaf(p, (float)x1[k], acc[8 + k]);
        __builtin_amdgcn_s_setprio(0);
        rv = rn1; rn1 = rn2; av = an; e += 8;
    }
    // mean edge attr (reduce esum over the 8 edge-slot groups)
    esum += __shfl_xor(esum, 8);
    esum += __shfl_xor(esum, 16);
    esum += __shfl_xor(esum, 32);
    float mean = esum / (float)max(len, 1);
    // virtual self-loop (counted once: edge-slot group 0 only; row preloaded)
    float aself = aslf + adn + mean * wdh;
    aself = fmaxf(aself, 0.2f * aself);
    float pself = exp2f(aself);
    if (eo == 0) {
        denom += pself;
        const _Float16* x0 = (const _Float16*)&sv0;
        const _Float16* x1 = (const _Float16*)&sv1;
#pragma unroll
        for (int k = 0; k < 8; ++k) acc[k]     = fmaf(pself, (float)x0[k], acc[k]);
#pragma unroll
        for (int k = 0; k < 8; ++k) acc[8 + k] = fmaf(pself, (float)x1[k], acc[8 + k]);
    }
    // denom over the 8 edge slots of this head
    denom += __shfl_xor(denom, 8);
    denom += __shfl_xor(denom, 16);
    denom += __shfl_xor(denom, 32);
    float invd = 1.0f / (denom + EPS);
    // normalized partials -> LDS [channel][lane], stride 65 (conflict-free both ways)
    float* hw = &hs[w * 1040];
#pragma unroll
    for (int k = 0; k < 16; ++k) hw[k * 65 + l] = acc[k] * invd;
    // sum 64 lanes per channel = sum over edges AND heads (head-mean numerator)
    int c = l & 15, qt = l >> 4;
    const float* rp = &hw[c * 65 + qt * 16];
    float v = 0.f;
#pragma unroll
    for (int i = 0; i < 16; ++i) v += rp[i];
    v += __shfl_xor(v, 16);
    v += __shfl_xor(v, 32);
    // t = relu(mean + b1); fused hh = t @ W2 (lane (c,qt) covers cols 2qt,2qt+1)
    float t = fmaxf(v * 0.125f + b1[c], 0.f);
    float p0 = t * W2[c * 8 + 2 * qt];
    float p1 = t * W2[c * 8 + 2 * qt + 1];
#pragma unroll
    for (int m = 1; m <= 8; m <<= 1) {
        p0 += __shfl_xor(p0, m);
        p1 += __shfl_xor(p1, m);
    }
    if (c == 0) *(float2*)&hh2[(size_t)wid * 8 + 2 * qt] = make_float2(p0, p1);
    float sd = p0 * as2w[2 * qt] + p1 * as2w[2 * qt + 1];
    float dd = p0 * ad2w[2 * qt] + p1 * ad2w[2 * qt + 1];
    sd += __shfl_xor(sd, 16); sd += __shfl_xor(sd, 32);
    dd += __shfl_xor(dd, 16); dd += __shfl_xor(dd, 32);
    if (l == 0) { asrc2[wid] = sd * LOG2E; adst2[wid] = dd * LOG2E; }
}

// ---------------- layer 2 aggregation (two streams, clamp-free, virtual self-loop) ------

__global__ __launch_bounds__(256) void k_agg2(
    int N, const int* __restrict__ rowptr, const int* __restrict__ bpref,
    const int2* __restrict__ rec,
    const float* __restrict__ asrc2, const float* __restrict__ adst2,
    const float* __restrict__ wed,
    const float* __restrict__ hh, const float* __restrict__ b2, float* __restrict__ out) {
    int wid = (blockIdx.x * blockDim.x + threadIdx.x) >> 6;
    if (wid >= N) return;
    int l = threadIdx.x & 63;
    int eo = l >> 3, c = l & 7;
    int start = rowptr[wid] + bpref[wid >> 8];
    int end   = rowptr[wid + 1] + bpref[(wid + 1) >> 8];
    int len = end - start;
    int G = (len + 7) >> 3;
    int nIt = (G + 1) >> 1;
    int startB = start + (nIt << 3);
    int endA = min(startB, end);
    float adn = adst2[wid];   // pre-scaled
    float w2 = wed[8];        // pre-scaled
    float hself = hh[(size_t)wid * 8 + c];   // self term: issue early
    float aslf = asrc2[wid];

    float acc = 0.0f, denom = 0.0f, esum = 0.0f;
    int eA = start + eo, eB = startB + eo;
    int2 rvA  = rec[eA];
    int2 rnA1 = rec[eA + 8];
    int2 rvB  = rec[eB];
    int2 rnB1 = rec[eB + 8];
    float avA = asrc2[rvA.x];
    float avB = asrc2[rvB.x];
    for (int it = 0; it < nIt; ++it) {
        float hvA = hh[(size_t)rvA.x * 8 + c];
        float hvB = hh[(size_t)rvB.x * 8 + c];
        int2 rnA2 = rec[eA + 16];
        int2 rnB2 = rec[eB + 16];
        float anA = asrc2[rnA1.x];
        float anB = asrc2[rnB1.x];
        float wA = __int_as_float(rvA.y);
        float wB = __int_as_float(rvB.y);
        float aA = avA + adn + wA * w2;
        aA = fmaxf(aA, 0.2f * aA);
        bool vA = (eA < endA);
        float pA = vA ? exp2f(aA) : 0.0f;
        float aB = avB + adn + wB * w2;
        aB = fmaxf(aB, 0.2f * aB);
        bool vB = (eB < end);
        float pB = vB ? exp2f(aB) : 0.0f;
        esum += (vA ? wA : 0.f) + (vB ? wB : 0.f);
        denom += pA + pB;
        acc = fmaf(pA, hvA, fmaf(pB, hvB, acc));
        rvA = rnA1; rnA1 = rnA2; avA = anA; eA += 8;
        rvB = rnB1; rnB1 = rnB2; avB = anB; eB += 8;
    }
    // mean attr + virtual self-loop (counted once via eo==0; hself preloaded)
    esum += __shfl_xor(esum, 8); esum += __shfl_xor(esum, 16); esum += __shfl_xor(esum, 32);
    float mean = esum / (float)max(len, 1);
    float aself = aslf + adn + mean * w2;
    aself = fmaxf(aself, 0.2f * aself);
    float pself = exp2f(aself);
    if (eo == 0) {
        denom += pself;
        acc = fmaf(pself, hself, acc);
    }
    acc += __shfl_xor(acc, 8);  acc += __shfl_xor(acc, 16);  acc += __shfl_xor(acc, 32);
    denom += __shfl_xor(denom, 8); denom += __shfl_xor(denom, 16); denom += __shfl_xor(denom, 32);
    if (l < 8) out[(size_t)wid * 8 + l] = acc / (denom + EPS) + b2[l];
}

// ---------------- launch ----------------

extern "C" void kernel_launch(void* const* d_in, const int* in_sizes, int n_in,
                              void* d_out, int out_size, void* d_ws, size_t ws_size,
                              hipStream_t stream) {
    const float* x        = (const float*)d_in[0];
    const int*   ei       = (const int*)d_in[1];
    const float* ea       = (const float*)d_in[2];
    const float* W1       = (const float*)d_in[3];
    const float* We1      = (const float*)d_in[4];
    const float* att_src1 = (const float*)d_in[5];
    const float* att_dst1 = (const float*)d_in[6];
    const float* att_edge1= (const float*)d_in[7];
    const float* b1       = (const float*)d_in[8];
    const float* W2       = (const float*)d_in[9];
    const float* We2      = (const float*)d_in[10];
    const float* att_src2 = (const float*)d_in[11];
    const float* att_dst2 = (const float*)d_in[12];
    const float* att_edge2= (const float*)d_in[13];
    const float* b2       = (const float*)d_in[14];
    float* out = (float*)d_out;

    const int N = in_sizes[0] / 64;
    const int E = in_sizes[2];
    const int CH = (E + RB - 1) / RB;
    const int NB64 = (N + 63) / 64;
    const int Mpad = NB64 * 64;
    const int SB = (E + 32 + 255) / 256;     // scatter blocks (2 edges/thread, incl. pad)
    const int GB = Mpad / 32;                // gemm blocks (32-row tiles)

    char* p = (char*)d_ws;
    auto alloc = [&](size_t bytes) { void* r = (void*)p; p += (bytes + 255) & ~(size_t)255; return r; };
    int*   rowptr = (int*)  alloc((size_t)(N + 1) * 4);
    int*   bsums  = (int*)  alloc((size_t)4096 * 4);
    int*   bpref  = (int*)  alloc((size_t)4096 * 4);
    int*   done   = (int*)  alloc(256);
    int2*  rec    = (int2*) alloc((size_t)(E + 32) * 8);
    _Float16* Wpk = (_Float16*)alloc((size_t)8192 * 2);
    _Float16* xh  = (_Float16*)alloc((size_t)Mpad * 64 * 2);
    __half* h1    = (__half*)alloc((size_t)Mpad * 128 * 2);
    float* asrc1  = (float*)alloc((size_t)N * 8 * 4);
    float* adst1  = (float*)alloc((size_t)N * 8 * 4);
    float* hh2    = (float*)alloc((size_t)N * 8 * 4);
    float* asrc2  = (float*)alloc((size_t)N * 4);
    float* adst2  = (float*)alloc((size_t)N * 4);
    float* wed    = (float*)alloc(16 * 4);
    unsigned short* rank = (unsigned short*)alloc((size_t)E * 2);
    unsigned short* H    = (unsigned short*)alloc((size_t)RNG * RB * NRR * 2);

    const int nbN = (N + 255) / 256;
    const int nbX = Mpad / 32;

    hipLaunchKernelGGL(k_prephist, dim3(RNG * RB + nbX + 1), dim3(256), 0, stream,
                       E, CH, ei, H, rank,
                       N, nbX, x, xh, W1, Wpk, We1, att_edge1, We2, att_edge2, wed, done);
    hipLaunchKernelGGL(k_cntscan,  dim3(nbN), dim3(256), 0, stream, N, nbN, H, rowptr,
                       bsums, bpref, done);
    hipLaunchKernelGGL(k_scatgemm, dim3(SB + GB), dim3(128), 0, stream, E, CH, SB, ei, ea,
                       rowptr, bpref, H, rank, rec, N, xh, Wpk, att_src1, att_dst1, h1, asrc1, adst1);
    hipLaunchKernelGGL(k_agg1,     dim3((N + 3) / 4), dim3(256), 0, stream, N, rowptr, bpref, rec,
                       asrc1, adst1, wed, h1, b1, W2, att_src2, att_dst2, hh2, asrc2, adst2);
    hipLaunchKernelGGL(k_agg2,     dim3((N + 3) / 4), dim3(256), 0, stream, N, rowptr, bpref, rec,
                       asrc2, adst2, wed, hh2, b2, out);
}

// Round 18
// 121.924 us; speedup vs baseline: 1.1197x; 1.1197x over previous
//
#include <hip/hip_runtime.h>
#include <hip/hip_fp16.h>
#include <math.h>

#define EPS 1e-16f
#define LOG2E 1.44269504088896340736f

typedef _Float16 half8 __attribute__((ext_vector_type(8)));
typedef float floatx4 __attribute__((ext_vector_type(4)));

// CSR-build geometry: 4 dst-ranges x 16384 nodes (64KB LDS histogram),
// 64 edge-chunk blocks per range -> 256 blocks (all CUs).
#define RNG 4
#define NRR 16384
#define RB  64

// ---------------- fused: hist (blocks < 256) + misc x->fp16 / W1 pack / wed (rest) ------

__global__ __launch_bounds__(256) void k_prephist(
    int E, int CH, const int* __restrict__ ei,
    unsigned short* __restrict__ H, unsigned short* __restrict__ rank,
    int N, int nbX, const float* __restrict__ x, _Float16* __restrict__ xh,
    const float* __restrict__ W1, _Float16* __restrict__ Wpk,
    const float* __restrict__ We1, const float* __restrict__ ae1,
    const float* __restrict__ We2, const float* __restrict__ ae2,
    float* __restrict__ wed) {
    __shared__ int hist[NRR];
    int bid = blockIdx.x;
    if (bid < RNG * RB) {
        // ---- histogram ----
        int r = bid / RB, b = bid % RB;
        for (int i = threadIdx.x; i < NRR; i += 256) hist[i] = 0;
        __syncthreads();
        int lo = b * CH, hi = min(E, (b + 1) * CH);
        int rlo = r << 14;
#pragma unroll 4
        for (int e = lo + threadIdx.x; e < hi; e += 256) {
            int d = ei[E + e];
            int dr = d - rlo;
            if ((unsigned)dr < NRR) rank[e] = (unsigned short)atomicAdd(&hist[dr], 1);
        }
        __syncthreads();
        unsigned short* Hb = H + (size_t)bid * NRR;
        for (int i = threadIdx.x; i < NRR; i += 256) Hb[i] = (unsigned short)hist[i];
        return;
    }
    int mb = bid - RNG * RB;
    if (mb < nbX) {
        // ---- x -> fp16, zero-padded ----
        int t = mb * 256 + threadIdx.x;
        int row = t >> 3;
        half8 h;
        if (row < N) {
            const float4* pp = (const float4*)(x + (size_t)t * 8);
            float4 f0 = pp[0], f1 = pp[1];
            h[0] = (_Float16)f0.x; h[1] = (_Float16)f0.y; h[2] = (_Float16)f0.z; h[3] = (_Float16)f0.w;
            h[4] = (_Float16)f1.x; h[5] = (_Float16)f1.y; h[6] = (_Float16)f1.z; h[7] = (_Float16)f1.w;
        } else {
#pragma unroll
            for (int i = 0; i < 8; ++i) h[i] = (_Float16)0.0f;
        }
        *(half8*)(xh + (size_t)t * 8) = h;
    } else {
        // ---- W1 -> MFMA B-fragment order + wed dots (pre-scaled by log2e) ----
        int t = threadIdx.x;
        for (int i = 0; i < 32; ++i) {
            int idx = i * 256 + t;           // 8192 total
            int j  = idx & 7;
            int lq = (idx >> 3) & 63;
            int ks = (idx >> 9) & 1;
            int ct = idx >> 10;
            int k   = ks * 32 + (lq >> 4) * 8 + j;
            int col = ct * 16 + (lq & 15);
            Wpk[idx] = (_Float16)W1[k * 128 + col];
        }
        if (t < 8) {
            float ssum = 0.0f;
            for (int cc = 0; cc < 16; ++cc) ssum += We1[t * 16 + cc] * ae1[t * 16 + cc];
            wed[t] = ssum * LOG2E;
        }
        if (t == 8) {
            float ssum = 0.0f;
            for (int cc = 0; cc < 8; ++cc) ssum += We2[cc] * ae2[cc];
            wed[8] = ssum * LOG2E;
        }
    }
}

// fused: per-node scan of the RB block-histograms (in place, u16) + block-level
// exclusive scan of cnt into rowptr-local + bsums.
__global__ __launch_bounds__(256) void k_cntscan(int N, unsigned short* __restrict__ H,
                                                 int* rowptr, int* bsums) {
    __shared__ int sm[256];
    int t = threadIdx.x;
    int n = blockIdx.x * 256 + t;
    int sum = 0;
    if (n < N) {
        int r = n >> 14, dr = n & (NRR - 1);
        size_t base = ((size_t)(r * RB)) * NRR + dr;
#pragma unroll 8
        for (int b = 0; b < RB; ++b) {
            size_t idx = base + (size_t)b * NRR;
            int v = H[idx];
            H[idx] = (unsigned short)sum;
            sum += v;
        }
    }
    int val = (n < N) ? sum : 0;
    sm[t] = val; __syncthreads();
    for (int ofs = 1; ofs < 256; ofs <<= 1) {
        int v = (t >= ofs) ? sm[t - ofs] : 0;
        __syncthreads();
        sm[t] += v;
        __syncthreads();
    }
    if (n < N) rowptr[n] = sm[t] - val;
    if (t == 255) bsums[blockIdx.x] = sm[255];
}

// each block derives its own bsums prefix (nb <= 256) and adds; block 0 writes rowptr[N]
__global__ __launch_bounds__(256) void k_scanadd(int nb, int N, const int* __restrict__ bsums,
                                                 int* rowptr) {
    __shared__ int sm[256];
    int t = threadIdx.x;
    int bid = blockIdx.x;
    sm[t] = (t < nb) ? bsums[t] : 0;
    __syncthreads();
    for (int ofs = 1; ofs < 256; ofs <<= 1) {
        int v = (t >= ofs) ? sm[t - ofs] : 0;
        __syncthreads();
        sm[t] += v;
        __syncthreads();
    }
    int prefix = (bid > 0) ? sm[bid - 1] : 0;
    int n = bid * 256 + t;
    if (n < N) rowptr[n] += prefix;
    if (bid == 0 && t == 0) rowptr[N] = sm[nb - 1];
}

// ---------------- fused: scatter (blocks < SB) + layer-1 MFMA gemm (rest) ----------------
// 128-thread blocks; gemm uses a 2-wave 16.9KB LDS slab so scatter occupancy stays high.

#define LDSP 132

__global__ __launch_bounds__(128) void k_scatgemm(
    int E, int CH, int SB, const int* __restrict__ ei, const float* __restrict__ ea,
    const int* __restrict__ rowptr, const unsigned short* __restrict__ H,
    const unsigned short* __restrict__ rank, int2* __restrict__ rec,
    int N, const _Float16* __restrict__ xh, const _Float16* __restrict__ Wpk,
    const float* __restrict__ att_s, const float* __restrict__ att_d,
    __half* __restrict__ h1, float* __restrict__ asrc, float* __restrict__ adst) {
    __shared__ float hs[2 * 16 * LDSP];
    if ((int)blockIdx.x < SB) {
        // ---- scatter: one packed 8B store per edge (L2-coalesced) + 32 sentinel pads ----
        int e = blockIdx.x * 128 + threadIdx.x;
        if (e < E) {
            int s = ei[e], d = ei[E + e];
            int r = d >> 14, dr = d & (NRR - 1);
            int b = e / CH;
            int pos = rowptr[d] + (int)H[((size_t)(r * RB + b)) * NRR + dr] + (int)rank[e];
            rec[pos] = make_int2(s, __float_as_int(ea[e]));
        } else if (e < E + 32) {
            rec[e] = make_int2(0, 0);    // sentinel pad: valid node id, attr 0
        }
        return;
    }
    // ---- gemm: 32-row tile; wave w computes rows [blk*32+w*16,+16) x 128 ----
    int blk = blockIdx.x - SB;
    int tid = threadIdx.x;
    int w = tid >> 6, l = tid & 63;
    int row0 = blk * 32 + w * 16;
    int arow = row0 + (l & 15);
    half8 a0 = *(const half8*)(xh + (size_t)arow * 64 + (l >> 4) * 8);
    half8 a1 = *(const half8*)(xh + (size_t)arow * 64 + 32 + (l >> 4) * 8);
    float* base = &hs[w * 16 * LDSP];
    int r0 = (l >> 4) * 4;
#pragma unroll
    for (int ct = 0; ct < 8; ++ct) {
        half8 b0 = *(const half8*)(Wpk + ((ct * 2 + 0) * 64 + l) * 8);
        half8 b1 = *(const half8*)(Wpk + ((ct * 2 + 1) * 64 + l) * 8);
        floatx4 acc = {0.f, 0.f, 0.f, 0.f};
        acc = __builtin_amdgcn_mfma_f32_16x16x32_f16(a0, b0, acc, 0, 0, 0);
        acc = __builtin_amdgcn_mfma_f32_16x16x32_f16(a1, b1, acc, 0, 0, 0);
        int col = ct * 16 + (l & 15);
#pragma unroll
        for (int i = 0; i < 4; ++i)
            base[(r0 + i) * LDSP + col] = acc[i];
    }
    __syncthreads();
    int r = tid >> 2, g = tid & 3;      // r in 0..31
    int rg = blk * 32 + r;
    if (rg >= N) return;
    float v[32];
    const float* rp = &hs[r * LDSP + g * 32];
#pragma unroll
    for (int j = 0; j < 8; ++j) {
        floatx4 t4 = *(const floatx4*)(rp + j * 4);
        v[j * 4 + 0] = t4[0]; v[j * 4 + 1] = t4[1];
        v[j * 4 + 2] = t4[2]; v[j * 4 + 3] = t4[3];
    }
    float vs0 = 0.f, vs1 = 0.f, vd0 = 0.f, vd1 = 0.f;
    const float4* as4 = (const float4*)(att_s + g * 32);
    const float4* ad4 = (const float4*)(att_d + g * 32);
#pragma unroll
    for (int j = 0; j < 4; ++j) {
        float4 a4 = as4[j], d4 = ad4[j];
        vs0 += v[j*4+0]*a4.x + v[j*4+1]*a4.y + v[j*4+2]*a4.z + v[j*4+3]*a4.w;
        vd0 += v[j*4+0]*d4.x + v[j*4+1]*d4.y + v[j*4+2]*d4.z + v[j*4+3]*d4.w;
    }
#pragma unroll
    for (int j = 4; j < 8; ++j) {
        float4 a4 = as4[j], d4 = ad4[j];
        vs1 += v[j*4+0]*a4.x + v[j*4+1]*a4.y + v[j*4+2]*a4.z + v[j*4+3]*a4.w;
        vd1 += v[j*4+0]*d4.x + v[j*4+1]*d4.y + v[j*4+2]*d4.z + v[j*4+3]*d4.w;
    }
    union { __half h[32]; float4 f4[4]; } u;
#pragma unroll
    for (int i = 0; i < 32; ++i) u.h[i] = __float2half(v[i]);
    float4* hp = (float4*)(h1 + (size_t)rg * 128 + g * 32);
#pragma unroll
    for (int j = 0; j < 4; ++j) hp[j] = u.f4[j];
    asrc[rg * 8 + g * 2]     = vs0 * LOG2E;
    asrc[rg * 8 + g * 2 + 1] = vs1 * LOG2E;
    adst[rg * 8 + g * 2]     = vd0 * LOG2E;
    adst[rg * 8 + g * 2 + 1] = vd1 * LOG2E;
}

// ---------------- layer 1 aggregation (virtual self-loop, clamp-free) + fused L2 dense --
// one wave per node; lane l = (eo = l>>3 edge slot, hd = l&7 head). rec is padded with
// 32 sentinels -> no min/has clamps; invalid lanes masked by e<end only.

__global__ __launch_bounds__(256) void k_agg1(
    int N, const int* __restrict__ rowptr, const int2* __restrict__ rec,
    const float* __restrict__ asrc1, const float* __restrict__ adst1,
    const float* __restrict__ wed,
    const __half* __restrict__ h1v, const float* __restrict__ b1,
    const float* __restrict__ W2, const float* __restrict__ as2w, const float* __restrict__ ad2w,
    float* __restrict__ hh2, float* __restrict__ asrc2, float* __restrict__ adst2) {
    __shared__ float hs[4 * 1040];   // 4 waves x 16 rows x 65 floats (stride 65: conflict-free)
    int tid = threadIdx.x;
    int wid = (blockIdx.x * blockDim.x + tid) >> 6;
    if (wid >= N) return;
    int l = tid & 63, w = tid >> 6;
    int eo = l >> 3, hd = l & 7;
    int start = rowptr[wid], end = rowptr[wid + 1];
    int len = end - start;               // real edges
    float adn = adst1[wid * 8 + hd];     // pre-scaled by log2e
    float wdh = wed[hd];                 // pre-scaled by log2e
    const _Float16* h1p = (const _Float16*)h1v;

    float acc[16];
#pragma unroll
    for (int k = 0; k < 16; ++k) acc[k] = 0.f;
    float denom = 0.f, esum = 0.f;
    int e = start + eo;
    int2 rv  = rec[e];
    int2 rn1 = rec[e + 8];
    float av = asrc1[rv.x * 8 + hd];
    int nIt = (len + 7) >> 3;
    for (int it = 0; it < nIt; ++it) {
        const _Float16* hr = h1p + (((size_t)rv.x) << 7) + hd * 16;
        float4 hv0 = *(const float4*)hr;          // addr register-ready (rv 2 iters old)
        float4 hv1 = *(const float4*)(hr + 8);
        int2 rn2 = rec[e + 16];                   // 2-ahead rec (pad-safe)
        float an = asrc1[rn1.x * 8 + hd];         // 1-ahead asrc
        float wgt = __int_as_float(rv.y);
        float a = av + adn + wgt * wdh;
        a = fmaxf(a, 0.2f * a);                   // leaky-relu (scale-commutes)
        bool valid = (e < end);
        float p = valid ? exp2f(a) : 0.f;
        esum += valid ? wgt : 0.f;
        denom += p;
        const _Float16* x0 = (const _Float16*)&hv0;
        const _Float16* x1 = (const _Float16*)&hv1;
#pragma unroll
        for (int k = 0; k < 8; ++k) acc[k]     = fmaf(p, (float)x0[k], acc[k]);
#pragma unroll
        for (int k = 0; k < 8; ++k) acc[8 + k] = fmaf(p, (float)x1[k], acc[8 + k]);
        rv = rn1; rn1 = rn2; av = an; e += 8;
    }
    // mean edge attr (reduce esum over the 8 edge-slot groups)
    esum += __shfl_xor(esum, 8);
    esum += __shfl_xor(esum, 16);
    esum += __shfl_xor(esum, 32);
    float mean = esum / (float)max(len, 1);
    // virtual self-loop (counted once: edge-slot group 0 only)
    float aself = asrc1[wid * 8 + hd] + adn + mean * wdh;
    aself = fmaxf(aself, 0.2f * aself);
    float pself = exp2f(aself);
    if (eo == 0) {
        denom += pself;
        const _Float16* hr = h1p + (((size_t)wid) << 7) + hd * 16;
        float4 hv0 = *(const float4*)hr;
        float4 hv1 = *(const float4*)(hr + 8);
        const _Float16* x0 = (const _Float16*)&hv0;
        const _Float16* x1 = (const _Float16*)&hv1;
#pragma unroll
        for (int k = 0; k < 8; ++k) acc[k]     = fmaf(pself, (float)x0[k], acc[k]);
#pragma unroll
        for (int k = 0; k < 8; ++k) acc[8 + k] = fmaf(pself, (float)x1[k], acc[8 + k]);
    }
    // denom over the 8 edge slots of this head
    denom += __shfl_xor(denom, 8);
    denom += __shfl_xor(denom, 16);
    denom += __shfl_xor(denom, 32);
    float invd = 1.0f / (denom + EPS);
    // normalized partials -> LDS [channel][lane], stride 65 (conflict-free both ways)
    float* hw = &hs[w * 1040];
#pragma unroll
    for (int k = 0; k < 16; ++k) hw[k * 65 + l] = acc[k] * invd;
    // sum 64 lanes per channel = sum over edges AND heads (head-mean numerator)
    int c = l & 15, qt = l >> 4;
    const float* rp = &hw[c * 65 + qt * 16];
    float v = 0.f;
#pragma unroll
    for (int i = 0; i < 16; ++i) v += rp[i];
    v += __shfl_xor(v, 16);
    v += __shfl_xor(v, 32);
    // t = relu(mean + b1); fused hh = t @ W2 (lane (c,qt) covers cols 2qt,2qt+1)
    float t = fmaxf(v * 0.125f + b1[c], 0.f);
    float p0 = t * W2[c * 8 + 2 * qt];
    float p1 = t * W2[c * 8 + 2 * qt + 1];
#pragma unroll
    for (int m = 1; m <= 8; m <<= 1) {
        p0 += __shfl_xor(p0, m);
        p1 += __shfl_xor(p1, m);
    }
    if (c == 0) *(float2*)&hh2[(size_t)wid * 8 + 2 * qt] = make_float2(p0, p1);
    float sd = p0 * as2w[2 * qt] + p1 * as2w[2 * qt + 1];
    float dd = p0 * ad2w[2 * qt] + p1 * ad2w[2 * qt + 1];
    sd += __shfl_xor(sd, 16); sd += __shfl_xor(sd, 32);
    dd += __shfl_xor(dd, 16); dd += __shfl_xor(dd, 32);
    if (l == 0) { asrc2[wid] = sd * LOG2E; adst2[wid] = dd * LOG2E; }
}

// ---------------- layer 2 aggregation (two streams, clamp-free, virtual self-loop) ------

__global__ __launch_bounds__(256) void k_agg2(
    int N, const int* __restrict__ rowptr, const int2* __restrict__ rec,
    const float* __restrict__ asrc2, const float* __restrict__ adst2,
    const float* __restrict__ wed,
    const float* __restrict__ hh, const float* __restrict__ b2, float* __restrict__ out) {
    int wid = (blockIdx.x * blockDim.x + threadIdx.x) >> 6;
    if (wid >= N) return;
    int l = threadIdx.x & 63;
    int eo = l >> 3, c = l & 7;
    int start = rowptr[wid], end = rowptr[wid + 1];
    int len = end - start;
    int G = (len + 7) >> 3;
    int nIt = (G + 1) >> 1;
    int startB = start + (nIt << 3);
    int endA = min(startB, end);
    float adn = adst2[wid];   // pre-scaled
    float w2 = wed[8];        // pre-scaled

    float acc = 0.0f, denom = 0.0f, esum = 0.0f;
    int eA = start + eo, eB = startB + eo;
    int2 rvA  = rec[eA];
    int2 rnA1 = rec[eA + 8];
    int2 rvB  = rec[eB];
    int2 rnB1 = rec[eB + 8];
    float avA = asrc2[rvA.x];
    float avB = asrc2[rvB.x];
    for (int it = 0; it < nIt; ++it) {
        float hvA = hh[(size_t)rvA.x * 8 + c];
        float hvB = hh[(size_t)rvB.x * 8 + c];
        int2 rnA2 = rec[eA + 16];
        int2 rnB2 = rec[eB + 16];
        float anA = asrc2[rnA1.x];
        float anB = asrc2[rnB1.x];
        float wA = __int_as_float(rvA.y);
        float wB = __int_as_float(rvB.y);
        float aA = avA + adn + wA * w2;
        aA = fmaxf(aA, 0.2f * aA);
        bool vA = (eA < endA);
        float pA = vA ? exp2f(aA) : 0.0f;
        float aB = avB + adn + wB * w2;
        aB = fmaxf(aB, 0.2f * aB);
        bool vB = (eB < end);
        float pB = vB ? exp2f(aB) : 0.0f;
        esum += (vA ? wA : 0.f) + (vB ? wB : 0.f);
        denom += pA + pB;
        acc = fmaf(pA, hvA, fmaf(pB, hvB, acc));
        rvA = rnA1; rnA1 = rnA2; avA = anA; eA += 8;
        rvB = rnB1; rnB1 = rnB2; avB = anB; eB += 8;
    }
    // mean attr + virtual self-loop (counted once via eo==0)
    esum += __shfl_xor(esum, 8); esum += __shfl_xor(esum, 16); esum += __shfl_xor(esum, 32);
    float mean = esum / (float)max(len, 1);
    float aself = asrc2[wid] + adn + mean * w2;
    aself = fmaxf(aself, 0.2f * aself);
    float pself = exp2f(aself);
    if (eo == 0) {
        denom += pself;
        acc = fmaf(pself, hh[(size_t)wid * 8 + c], acc);
    }
    acc += __shfl_xor(acc, 8);  acc += __shfl_xor(acc, 16);  acc += __shfl_xor(acc, 32);
    denom += __shfl_xor(denom, 8); denom += __shfl_xor(denom, 16); denom += __shfl_xor(denom, 32);
    if (l < 8) out[(size_t)wid * 8 + l] = acc / (denom + EPS) + b2[l];
}

// ---------------- launch ----------------

extern "C" void kernel_launch(void* const* d_in, const int* in_sizes, int n_in,
                              void* d_out, int out_size, void* d_ws, size_t ws_size,
                              hipStream_t stream) {
    const float* x        = (const float*)d_in[0];
    const int*   ei       = (const int*)d_in[1];
    const float* ea       = (const float*)d_in[2];
    const float* W1       = (const float*)d_in[3];
    const float* We1      = (const float*)d_in[4];
    const float* att_src1 = (const float*)d_in[5];
    const float* att_dst1 = (const float*)d_in[6];
    const float* att_edge1= (const float*)d_in[7];
    const float* b1       = (const float*)d_in[8];
    const float* W2       = (const float*)d_in[9];
    const float* We2      = (const float*)d_in[10];
    const float* att_src2 = (const float*)d_in[11];
    const float* att_dst2 = (const float*)d_in[12];
    const float* att_edge2= (const float*)d_in[13];
    const float* b2       = (const float*)d_in[14];
    float* out = (float*)d_out;

    const int N = in_sizes[0] / 64;
    const int E = in_sizes[2];
    const int CH = (E + RB - 1) / RB;
    const int NB64 = (N + 63) / 64;
    const int Mpad = NB64 * 64;
    const int SB = (E + 32 + 127) / 128;     // scatter blocks (incl. sentinel pad)
    const int GB = Mpad / 32;                // gemm blocks (32-row tiles)

    char* p = (char*)d_ws;
    auto alloc = [&](size_t bytes) { void* r = (void*)p; p += (bytes + 255) & ~(size_t)255; return r; };
    int*   rowptr = (int*)  alloc((size_t)(N + 1) * 4);
    int*   bsums  = (int*)  alloc((size_t)4096 * 4);
    int2*  rec    = (int2*) alloc((size_t)(E + 32) * 8);
    _Float16* Wpk = (_Float16*)alloc((size_t)8192 * 2);
    _Float16* xh  = (_Float16*)alloc((size_t)Mpad * 64 * 2);
    __half* h1    = (__half*)alloc((size_t)Mpad * 128 * 2);
    float* asrc1  = (float*)alloc((size_t)N * 8 * 4);
    float* adst1  = (float*)alloc((size_t)N * 8 * 4);
    float* hh2    = (float*)alloc((size_t)N * 8 * 4);
    float* asrc2  = (float*)alloc((size_t)N * 4);
    float* adst2  = (float*)alloc((size_t)N * 4);
    float* wed    = (float*)alloc(16 * 4);
    unsigned short* rank = (unsigned short*)alloc((size_t)E * 2);
    unsigned short* H    = (unsigned short*)alloc((size_t)RNG * RB * NRR * 2);

    const int nbN = (N + 255) / 256;
    const int nbX = Mpad / 32;

    hipLaunchKernelGGL(k_prephist, dim3(RNG * RB + nbX + 1), dim3(256), 0, stream,
                       E, CH, ei, H, rank,
                       N, nbX, x, xh, W1, Wpk, We1, att_edge1, We2, att_edge2, wed);
    hipLaunchKernelGGL(k_cntscan,  dim3(nbN), dim3(256), 0, stream, N, H, rowptr, bsums);
    hipLaunchKernelGGL(k_scanadd,  dim3(nbN), dim3(256), 0, stream, nbN, N, bsums, rowptr);
    hipLaunchKernelGGL(k_scatgemm, dim3(SB + GB), dim3(128), 0, stream, E, CH, SB, ei, ea,
                       rowptr, H, rank, rec, N, xh, Wpk, att_src1, att_dst1, h1, asrc1, adst1);
    hipLaunchKernelGGL(k_agg1,     dim3((N + 3) / 4), dim3(256), 0, stream, N, rowptr, rec,
                       asrc1, adst1, wed, h1, b1, W2, att_src2, att_dst2, hh2, asrc2, adst2);
    hipLaunchKernelGGL(k_agg2,     dim3((N + 3) / 4), dim3(256), 0, stream, N, rowptr, rec,
                       asrc2, adst2, wed, hh2, b2, out);
}